// Round 11
// baseline (124.376 us; speedup 1.0000x reference)
//
#include <hip/hip_runtime.h>

// y = x @ W_base^T + b + S * adapter(x);  adapter folds into the weight:
//   W_eff[o*64+e][i*64+d] = W_base[..] + S * U[d,i,o] * V[o,d,e]
// int8 GEMM path: per-row symmetric quant of X and W_eff (sx[m], sw[n]);
//   y = sx[m]*sw[n]*(i32 acc) + bias.
// This round: 128x128 tile / BK=128 / 4 waves / 64KB LDS -> TWO blocks per CU
// (independent barrier domains) so one block's MFMA burst overlaps the other
// block's LDS burst. Round-9 measured the two pipes fully SERIAL (4800 cyc/
// tile = 2614 MFMA + 2304 LDS) inside a single barrier domain. Swizzle,
// phase rhythm, and stage cadence carried over from round 9 unchanged.

typedef __attribute__((ext_vector_type(4))) float float4v;
typedef __attribute__((ext_vector_type(4))) int   int4v;

#define K_TOT 4096
#define M_TOT 4096
#define N_TOT 4096

// ------------- tiny transposes: Ut[i][o][d]=U[d][i][o], Vt[o][e][d]=V[o][d][e]
__global__ void trans_uv(const float* __restrict__ U, const float* __restrict__ V,
                         float* __restrict__ Ut, float* __restrict__ Vt) {
  int idx = blockIdx.x * 256 + threadIdx.x;
  if (idx < 262144) {
    int d = idx & 63, o = (idx >> 6) & 63, i = idx >> 12;
    Ut[idx] = U[(d * 64 + i) * 64 + o];
  } else {
    int j = idx - 262144;
    int d = j & 63, e = (j >> 6) & 63, o = j >> 12;
    Vt[j] = V[(o * 64 + d) * 64 + e];
  }
}

// ------------- fused quantize: one block per row (round-9 exact) ------------
__global__ __launch_bounds__(1024) void quant_rows(
    const float* __restrict__ W, const float* __restrict__ Ut,
    const float* __restrict__ Vt, const float* __restrict__ Sp,
    const float* __restrict__ X, char* __restrict__ Wq, char* __restrict__ Xq,
    float* __restrict__ sw, float* __restrict__ sx) {
  __shared__ float red[16];
  const int row = blockIdx.x;
  const int t = threadIdx.x;          // 0..1023, one 16B quad each
  const float s = Sp[0];
  float4v v;
  if (row < 4096) {
    const int o = row >> 6, e = row & 63;
    const int i = t >> 4, d0 = (t & 15) << 2;
    const float4v wv = *(const float4v*)(W + (size_t)row * 4096 + t * 4);
    const float4v u4 = *(const float4v*)(Ut + (i * 64 + o) * 64 + d0);
    const float4v v4 = *(const float4v*)(Vt + (o * 64 + e) * 64 + d0);
#pragma unroll
    for (int j = 0; j < 4; ++j) v[j] = wv[j] + s * u4[j] * v4[j];
  } else {
    v = *(const float4v*)(X + (size_t)(row - 4096) * 4096 + t * 4);
  }
  float m = fmaxf(fmaxf(fabsf(v[0]), fabsf(v[1])),
                  fmaxf(fabsf(v[2]), fabsf(v[3])));
#pragma unroll
  for (int off = 32; off; off >>= 1) m = fmaxf(m, __shfl_xor(m, off));
  if ((t & 63) == 0) red[t >> 6] = m;
  __syncthreads();
  if (t < 16) {
    float mm = red[t];
#pragma unroll
    for (int off = 8; off; off >>= 1) mm = fmaxf(mm, __shfl_xor(mm, off));
    if (t == 0) red[0] = mm;
  }
  __syncthreads();
  const float mx = red[0];
  const float inv = mx > 0.f ? 127.f / mx : 0.f;
  int q[4];
#pragma unroll
  for (int j = 0; j < 4; ++j) {
    int qi = __float2int_rn(v[j] * inv);
    q[j] = qi > 127 ? 127 : (qi < -127 ? -127 : qi);
  }
  const int packed = (q[0] & 0xff) | ((q[1] & 0xff) << 8) |
                     ((q[2] & 0xff) << 16) | (q[3] << 24);
  if (row < 4096) {
    ((int*)Wq)[(size_t)row * 1024 + t] = packed;
    if (t == 0) sw[row] = mx * (1.f / 127.f);
  } else {
    ((int*)Xq)[(size_t)(row - 4096) * 1024 + t] = packed;
    if (t == 0) sx[row - 4096] = mx * (1.f / 127.f);
  }
}

// ---------------- 128x128 i8 GEMM, 2 blocks/CU ------------------------------
#define GL16(g, l)                                                    \
  __builtin_amdgcn_global_load_lds(                                   \
      (__attribute__((address_space(1))) void*)(g),                   \
      (__attribute__((address_space(3))) void*)(l), 16, 0, 0)

#define BARRIER() asm volatile("s_barrier" ::: "memory")
#define VMC4() asm volatile("s_waitcnt vmcnt(4)" ::: "memory")
#define VMC0() asm volatile("s_waitcnt vmcnt(0)" ::: "memory")
#define VMNONE()

__global__ __launch_bounds__(256, 2) void gemm128(
    const char* __restrict__ A,     // [4096][4096] i8 (Xq)
    const char* __restrict__ Bq,    // [4096][4096] i8 (Wq)
    const float* __restrict__ bias,
    const float* __restrict__ sx,   // [4096] row scales of X
    const float* __restrict__ sw,   // [4096] row scales of W_eff
    float* __restrict__ C) {
  // [buf][op A=0/B=1][half: 64 rows][64 rows x 128 i8] = 64 KiB
  __shared__ char lds[2][2][2][8192];

  const int tid = threadIdx.x;
  const int w = tid >> 6;       // wave 0..3
  const int l = tid & 63;
  const int l15 = l & 15;
  const int hi = l >> 4;

  // XCD-aware bijective swizzle (1024 blocks, 1024 % 8 == 0)
  int b = blockIdx.x;
  b = (b & 7) * 128 + (b >> 3);
  const int brow = (b >> 5) * 128;   // 32 tile-rows
  const int bcol = (b & 31) * 128;   // 32 tile-cols

  const int wr = w >> 1;        // 0..1 -> 64-row half of A-tile
  const int wc = w & 1;         // 0..1 -> 64-col half of B-tile

  // read-side swizzle (round-3/9 family, measured 0 conflicts):
  // logical chunk (kk*4 + hi) ^ (row&7), 16B chunks, row%16 == l15
  const int b2 = (l15 >> 2) & 1;
  const int cx = hi ^ (l15 & 3);
  const int rdK0 = (((b2 ^ 0) << 2) | cx) << 4;   // kk=0 chunk byte offset
  const int rdK1 = (((b2 ^ 1) << 2) | cx) << 4;   // kk=1
  const int rowOff = l15 << 7;                    // l15 * 128 bytes

  // stage-side inverse: pass covers phys chunks (w*64 + l); row = w*8 + (l>>3)
  const int rowL = l >> 3;
  const int cL = (l & 7) ^ rowL;
  const char* pa = A + (size_t)(brow + w * 8 + rowL) * 4096 + cL * 16;
  const char* pb = Bq + (size_t)(bcol + w * 8 + rowL) * 4096 + cL * 16;
  const int ldsC0 = w * 1024;          // byte base, rows 0-31 of half
  const int ldsC1 = 4096 + w * 1024;   // rows 32-63

  // H selects the 64-row half; passes differ by +32 global rows.
#define STAGE(gp, BUF, OP, H, kt)                                           \
  do {                                                                      \
    GL16((gp) + (size_t)(H) * (64 * 4096) + (kt), &lds[BUF][OP][H][ldsC0]); \
    GL16((gp) + (size_t)(H) * (64 * 4096) + (32 * 4096) + (kt),             \
         &lds[BUF][OP][H][ldsC1]);                                          \
  } while (0)

  int4v acc[4][4];
#pragma unroll
  for (int m = 0; m < 4; ++m)
#pragma unroll
    for (int j = 0; j < 4; ++j) acc[m][j] = (int4v){0, 0, 0, 0};
  int4v af[4][2];    // A frags: 4 m-rows x 2 kk
  int4v bfr[4][2];   // B frags: 4 n x 2 kk (live whole tile)

#define READ_A(BUF)                                                         \
  _Pragma("unroll") for (int mm = 0; mm < 4; ++mm) {                        \
    const char* ap = &lds[BUF][0][wr][mm * 2048 + rowOff];                  \
    af[mm][0] = *(const int4v*)&ap[rdK0];                                   \
    af[mm][1] = *(const int4v*)&ap[rdK1];                                   \
  }

#define READ_B(BUF, NH)                                                     \
  _Pragma("unroll") for (int jj = 0; jj < 2; ++jj) {                        \
    const char* bp = &lds[BUF][1][wc][((NH)*32 + jj * 16) * 128 + rowOff];  \
    bfr[(NH)*2 + jj][0] = *(const int4v*)&bp[rdK0];                         \
    bfr[(NH)*2 + jj][1] = *(const int4v*)&bp[rdK1];                         \
  }

#define MFMA8(NB)                                                           \
  do {                                                                      \
    __builtin_amdgcn_s_setprio(1);                                          \
    _Pragma("unroll") for (int mm = 0; mm < 4; ++mm) {                      \
      acc[mm][NB] = __builtin_amdgcn_mfma_i32_16x16x64_i8(                  \
          af[mm][0], bfr[NB][0], acc[mm][NB], 0, 0, 0);                     \
      acc[mm][NB] = __builtin_amdgcn_mfma_i32_16x16x64_i8(                  \
          af[mm][1], bfr[NB][1], acc[mm][NB], 0, 0, 0);                     \
    }                                                                       \
    __builtin_amdgcn_s_setprio(0);                                          \
  } while (0)

  // Cadence (round-9 rhythm): A(t+1)->buf^1 @P0/P1 (its A last read (t-1).P0,
  // >=4 barriers); B(t+2)->buf @P2/P3 (B(t) last read t.P1, >=1 barrier).
  // Ledger at t.P3: 12 outstanding; vmcnt(4) retires exactly tile t+1's 8.
#define TILE(BUF, TT, DA, DB, VM)                                          \
  do {                                                                     \
    READ_A(BUF); READ_B(BUF, 0);                                           \
    if (DA) STAGE(pa, 1 - (BUF), 0, 0, ((TT) + 1) * 128);                  \
    BARRIER(); MFMA8(0);                                                   \
    READ_B(BUF, 1);                                                        \
    if (DA) STAGE(pa, 1 - (BUF), 0, 1, ((TT) + 1) * 128);                  \
    BARRIER(); MFMA8(1);                                                   \
    if (DB) STAGE(pb, BUF, 1, 0, ((TT) + 2) * 128);                        \
    BARRIER(); MFMA8(2);                                                   \
    if (DB) STAGE(pb, BUF, 1, 1, ((TT) + 2) * 128);                        \
    VM();                                                                  \
    BARRIER(); MFMA8(3);                                                   \
  } while (0)

  // prologue: tile0 {A h0,h1, B h0,h1}, tile1 {B h0,h1}; retire tile0's 8,
  // leaving B(1)=4 in flight (steady-state invariant). A(1) staged at t0.P0/P1.
  STAGE(pa, 0, 0, 0, 0);
  STAGE(pa, 0, 0, 1, 0);
  STAGE(pb, 0, 1, 0, 0);
  STAGE(pb, 0, 1, 1, 0);
  STAGE(pb, 1, 1, 0, 128);
  STAGE(pb, 1, 1, 1, 128);
  VMC4();
  BARRIER();

  for (int t = 0; t < 30; t += 2) {
    TILE(0, t, 1, 1, VMC4);
    TILE(1, t + 1, 1, 1, VMC4);
  }
  TILE(0, 30, 1, 0, VMC0);   // stages A(31); B(32) skipped; drain everything
  TILE(1, 31, 0, 0, VMNONE); // nothing staged, nothing waited

  // epilogue: C/D layout col = lane&15, row = (lane>>4)*4 + v
  const int r0 = brow + wr * 64 + (l >> 4) * 4;
  const int c0 = bcol + wc * 64;
  float sxr[4][4];
#pragma unroll
  for (int m = 0; m < 4; ++m)
#pragma unroll
    for (int v = 0; v < 4; ++v) sxr[m][v] = sx[r0 + m * 16 + v];
#pragma unroll
  for (int j = 0; j < 4; ++j) {
    const int col = c0 + j * 16 + l15;
    const float bv = bias[col];
    const float swc = sw[col];
#pragma unroll
    for (int m = 0; m < 4; ++m) {
      const int row = r0 + m * 16;
#pragma unroll
      for (int v = 0; v < 4; ++v)
        C[(size_t)(row + v) * N_TOT + col] =
            (float)acc[m][j][v] * (sxr[m][v] * swc) + bv;
    }
  }
}

extern "C" void kernel_launch(void* const* d_in, const int* in_sizes, int n_in,
                              void* d_out, int out_size, void* d_ws, size_t ws_size,
                              hipStream_t stream) {
  const float* x = (const float*)d_in[0];    // [2,2048,4096]
  const float* Wb = (const float*)d_in[1];   // [4096,4096]
  const float* bb = (const float*)d_in[2];   // [4096]
  const float* U = (const float*)d_in[3];    // [64,64,64]
  const float* V = (const float*)d_in[4];    // [64,64,64]
  const float* S = (const float*)d_in[5];    // [1]
  float* out = (float*)d_out;

  char* Wq = (char*)d_ws;                               // 16 MiB
  char* Xq = Wq + (size_t)4096 * 4096;                  // 16 MiB
  float* sw = (float*)(Xq + (size_t)4096 * 4096);       // 16 KiB
  float* sx = sw + 4096;                                // 16 KiB
  // Ut/Vt scratch in d_out's head (1 MiB each) — overwritten by the GEMM later
  float* Ut = (float*)d_out;
  float* Vt = Ut + 262144;

  trans_uv<<<2048, 256, 0, stream>>>(U, V, Ut, Vt);
  quant_rows<<<8192, 1024, 0, stream>>>(Wb, Ut, Vt, S, x, Wq, Xq, sw, sx);

  gemm128<<<1024, 256, 0, stream>>>(Xq, Wq, bb, sx, sw, out);
}

// Round 12
// 96.147 us; speedup vs baseline: 1.2936x; 1.2936x over previous
//
#include <hip/hip_runtime.h>

// y = x @ W_base^T + b + S * adapter(x);  adapter folds into the weight:
//   W_eff[o*64+e][i*64+d] = W_base[..] + S * U[d,i,o] * V[o,d,e]
// int8 GEMM path: per-row symmetric quant of X and W_eff (sx[m], sw[n]);
//   y = sx[m]*sw[n]*(i32 acc) + bias.
// GEMM: round-9 verbatim (measured best: 64us, MfmaUtil 44%, 0 conflicts —
// at the MFMA+LDS serial floor of this structure; 3 overlap attempts all
// regressed). This round touches ONLY the prep kernel (512thr x 32B/thread,
// single-sync reduction).

typedef __attribute__((ext_vector_type(4))) float float4v;
typedef __attribute__((ext_vector_type(4))) int   int4v;
typedef __attribute__((ext_vector_type(2))) int   int2v;

#define K_TOT 4096
#define M_TOT 4096
#define N_TOT 4096

// ------------- tiny transposes: Ut[i][o][d]=U[d][i][o], Vt[o][e][d]=V[o][d][e]
__global__ void trans_uv(const float* __restrict__ U, const float* __restrict__ V,
                         float* __restrict__ Ut, float* __restrict__ Vt) {
  int idx = blockIdx.x * 256 + threadIdx.x;
  if (idx < 262144) {
    int d = idx & 63, o = (idx >> 6) & 63, i = idx >> 12;
    Ut[idx] = U[(d * 64 + i) * 64 + o];
  } else {
    int j = idx - 262144;
    int d = j & 63, e = (j >> 6) & 63, o = j >> 12;
    Vt[j] = V[(o * 64 + d) * 64 + e];
  }
}

// ------------- fused quantize: one block per row, 512 thr x 8 floats --------
// rows 0..4095   : W_eff row (computed on the fly) -> Wq + sw[row]
// rows 4096..8191: X row                           -> Xq + sx[row-4096]
__global__ __launch_bounds__(512) void quant_rows(
    const float* __restrict__ W, const float* __restrict__ Ut,
    const float* __restrict__ Vt, const float* __restrict__ Sp,
    const float* __restrict__ X, char* __restrict__ Wq, char* __restrict__ Xq,
    float* __restrict__ sw, float* __restrict__ sx) {
  __shared__ float red[8];
  const int row = blockIdx.x;
  const int t = threadIdx.x;          // 0..511, cols t*8 .. t*8+7
  const int c0 = t << 3;
  const float s = Sp[0];
  float4v v0, v1;
  if (row < 4096) {
    const int o = row >> 6, e = row & 63;
    const int i = c0 >> 6, d0 = c0 & 63;   // 8 cols stay in one 64-block
    const float4v wv0 = *(const float4v*)(W + (size_t)row * 4096 + c0);
    const float4v wv1 = *(const float4v*)(W + (size_t)row * 4096 + c0 + 4);
    const float4v u40 = *(const float4v*)(Ut + (i * 64 + o) * 64 + d0);
    const float4v u41 = *(const float4v*)(Ut + (i * 64 + o) * 64 + d0 + 4);
    const float4v v40 = *(const float4v*)(Vt + (o * 64 + e) * 64 + d0);
    const float4v v41 = *(const float4v*)(Vt + (o * 64 + e) * 64 + d0 + 4);
#pragma unroll
    for (int j = 0; j < 4; ++j) {
      v0[j] = wv0[j] + s * u40[j] * v40[j];
      v1[j] = wv1[j] + s * u41[j] * v41[j];
    }
  } else {
    v0 = *(const float4v*)(X + (size_t)(row - 4096) * 4096 + c0);
    v1 = *(const float4v*)(X + (size_t)(row - 4096) * 4096 + c0 + 4);
  }
  float m = fmaxf(fmaxf(fmaxf(fabsf(v0[0]), fabsf(v0[1])),
                        fmaxf(fabsf(v0[2]), fabsf(v0[3]))),
                  fmaxf(fmaxf(fabsf(v1[0]), fabsf(v1[1])),
                        fmaxf(fabsf(v1[2]), fabsf(v1[3]))));
#pragma unroll
  for (int off = 32; off; off >>= 1) m = fmaxf(m, __shfl_xor(m, off));
  if ((t & 63) == 0) red[t >> 6] = m;
  __syncthreads();
  float mx = red[0];
#pragma unroll
  for (int r = 1; r < 8; ++r) mx = fmaxf(mx, red[r]);   // LDS broadcast reads
  const float inv = mx > 0.f ? 127.f / mx : 0.f;
  int q[8];
#pragma unroll
  for (int j = 0; j < 4; ++j) {
    int a = __float2int_rn(v0[j] * inv);
    int b2 = __float2int_rn(v1[j] * inv);
    q[j] = a > 127 ? 127 : (a < -127 ? -127 : a);
    q[4 + j] = b2 > 127 ? 127 : (b2 < -127 ? -127 : b2);
  }
  int2v pk;
  pk[0] = (q[0] & 0xff) | ((q[1] & 0xff) << 8) | ((q[2] & 0xff) << 16) |
          (q[3] << 24);
  pk[1] = (q[4] & 0xff) | ((q[5] & 0xff) << 8) | ((q[6] & 0xff) << 16) |
          (q[7] << 24);
  if (row < 4096) {
    *(int2v*)(Wq + (size_t)row * 4096 + c0) = pk;
    if (t == 0) sw[row] = mx * (1.f / 127.f);
  } else {
    *(int2v*)(Xq + (size_t)(row - 4096) * 4096 + c0) = pk;
    if (t == 0) sx[row - 4096] = mx * (1.f / 127.f);
  }
}

// ---------------- 256x256 i8 GEMM (round-9 verbatim) ------------------------
#define GL16(g, l)                                                    \
  __builtin_amdgcn_global_load_lds(                                   \
      (__attribute__((address_space(1))) void*)(g),                   \
      (__attribute__((address_space(3))) void*)(l), 16, 0, 0)

#define BARRIER() asm volatile("s_barrier" ::: "memory")
#define VMC6() asm volatile("s_waitcnt vmcnt(6)" ::: "memory")
#define VMC0() asm volatile("s_waitcnt vmcnt(0)" ::: "memory")
#define VMNONE()

__global__ __launch_bounds__(512, 2) void gemm256(
    const char* __restrict__ A,     // [4096][4096] i8 (Xq)
    const char* __restrict__ Bq,    // [4096][4096] i8 (Wq)
    const float* __restrict__ bias,
    const float* __restrict__ sx,   // [4096] row scales of X
    const float* __restrict__ sw,   // [4096] row scales of W_eff
    float* __restrict__ C) {
  // [buf][op A=0/B=1][row-half][128 rows][128 i8] = 128 KiB
  __shared__ char lds[2][2][2][16384];

  const int tid = threadIdx.x;
  const int w = tid >> 6;
  const int l = tid & 63;
  const int l15 = l & 15;
  const int hi = l >> 4;

  // XCD-aware bijective swizzle (256 blocks, 256 % 8 == 0)
  int b = blockIdx.x;
  b = (b & 7) * 32 + (b >> 3);
  const int brow = (b >> 4) * 256;
  const int bcol = (b & 15) * 256;

  const int wr = w >> 2;        // 0..1 -> 128-row half of A-tile
  const int wc = w & 3;         // 0..3 -> 64-row slice of B-tile
  const int wcH = wc >> 1, wcL = wc & 1;

  // read-side swizzle (round-3 family, measured 0 conflicts):
  // logical chunk (kk*4 + hi) ^ (row&7), 16B chunks, row%16 == l15
  const int b2 = (l15 >> 2) & 1;
  const int cx = hi ^ (l15 & 3);
  const int rdK0 = (((b2 ^ 0) << 2) | cx) << 4;   // kk=0 chunk byte offset
  const int rdK1 = (((b2 ^ 1) << 2) | cx) << 4;   // kk=1
  const int rowOff = l15 << 7;                    // l15 * 128 bytes

  // stage-side inverse: lane covers phys chunk (w*64 + l); row = w*8 + (l>>3)
  const int rowL = l >> 3;
  const int cL = (l & 7) ^ rowL;
  const char* pa = A + (size_t)(brow + w * 8 + rowL) * 4096 + cL * 16;
  const char* pb = Bq + (size_t)(bcol + w * 8 + rowL) * 4096 + cL * 16;
  const int ldsC0 = w * 1024;          // byte base, rows 0-63 of half
  const int ldsC1 = 8192 + w * 1024;   // rows 64-127

#define STAGE(gp, BUF, OP, H, kt)                                           \
  do {                                                                      \
    GL16((gp) + (size_t)(H) * (128 * 4096) + (kt), &lds[BUF][OP][H][ldsC0]);\
    GL16((gp) + (size_t)(H) * (128 * 4096) + (64 * 4096) + (kt),            \
         &lds[BUF][OP][H][ldsC1]);                                          \
  } while (0)

  int4v acc[8][4];
#pragma unroll
  for (int m = 0; m < 8; ++m)
#pragma unroll
    for (int j = 0; j < 4; ++j) acc[m][j] = (int4v){0, 0, 0, 0};
  int4v af[4][2];    // A frags: 4 m-rows x 2 kk
  int4v bfr[4][2];   // B frags: 4 n x 2 kk (live whole tile)

#define READ_A(BUF, MB)                                                     \
  _Pragma("unroll") for (int mm = 0; mm < 4; ++mm) {                        \
    const char* ap = &lds[BUF][0][wr][((MB) + mm) * 2048 + rowOff];         \
    af[mm][0] = *(const int4v*)&ap[rdK0];                                   \
    af[mm][1] = *(const int4v*)&ap[rdK1];                                   \
  }

#define READ_B(BUF, NH)                                                     \
  _Pragma("unroll") for (int jj = 0; jj < 2; ++jj) {                        \
    const char* bp =                                                        \
        &lds[BUF][1][wcH][((wcL)*64 + (NH)*32 + jj * 16) * 128 + rowOff];   \
    bfr[(NH)*2 + jj][0] = *(const int4v*)&bp[rdK0];                         \
    bfr[(NH)*2 + jj][1] = *(const int4v*)&bp[rdK1];                         \
  }

#define MFMA16(MB, NB)                                                      \
  do {                                                                      \
    __builtin_amdgcn_s_setprio(1);                                          \
    _Pragma("unroll") for (int mm = 0; mm < 4; ++mm)                        \
        _Pragma("unroll") for (int nn = 0; nn < 2; ++nn) {                  \
      acc[(MB) + mm][(NB) + nn] = __builtin_amdgcn_mfma_i32_16x16x64_i8(    \
          af[mm][0], bfr[(NB) + nn][0], acc[(MB) + mm][(NB) + nn], 0, 0, 0);\
      acc[(MB) + mm][(NB) + nn] = __builtin_amdgcn_mfma_i32_16x16x64_i8(    \
          af[mm][1], bfr[(NB) + nn][1], acc[(MB) + mm][(NB) + nn], 0, 0, 0);\
    }                                                                       \
    __builtin_amdgcn_s_setprio(0);                                          \
  } while (0)

  // Cadence (round-7/9, ledger-verified, race-free):
  //   P0: stage Ah1(t+1)->buf^1; P2: Bh0(t+2)->buf;
  //   P3: Bh1(t+2)+Ah0(t+2)->buf, vmcnt(6).
#define TILE(BUF, TT, DA1, DB, DA0, VM)                                    \
  do {                                                                     \
    READ_A(BUF, 0); READ_B(BUF, 0);                                        \
    if (DA1) STAGE(pa, 1 - (BUF), 0, 1, ((TT) + 1) * 128);                 \
    BARRIER(); MFMA16(0, 0);                                               \
    READ_B(BUF, 1);                                                        \
    BARRIER(); MFMA16(0, 2);                                               \
    READ_A(BUF, 4);                                                        \
    if (DB) STAGE(pb, BUF, 1, 0, ((TT) + 2) * 128);                        \
    BARRIER(); MFMA16(4, 0);                                               \
    if (DB) STAGE(pb, BUF, 1, 1, ((TT) + 2) * 128);                        \
    if (DA0) STAGE(pa, BUF, 0, 0, ((TT) + 2) * 128);                       \
    VM();                                                                  \
    BARRIER(); MFMA16(4, 2);                                               \
  } while (0)

  // prologue: tile0 {Ah0,Ah1,Bh0,Bh1}, tile1 {Bh0,Bh1,Ah0}; retire tile0's 8.
  STAGE(pa, 0, 0, 0, 0);
  STAGE(pa, 0, 0, 1, 0);
  STAGE(pb, 0, 1, 0, 0);
  STAGE(pb, 0, 1, 1, 0);
  STAGE(pb, 1, 1, 0, 128);
  STAGE(pb, 1, 1, 1, 128);
  STAGE(pa, 1, 0, 0, 128);
  VMC6();
  BARRIER();

  for (int t = 0; t < 30; t += 2) {
    TILE(0, t, 1, 1, 1, VMC6);
    TILE(1, t + 1, 1, 1, 1, VMC6);
  }
  TILE(0, 30, 1, 0, 0, VMC0);   // stages Ah1(31) only; drain everything
  TILE(1, 31, 0, 0, 0, VMNONE); // nothing staged, nothing waited

  // epilogue: C/D layout col = lane&15, row = (lane>>4)*4 + v
  const int r0 = brow + wr * 128 + (l >> 4) * 4;
  const int c0 = bcol + wc * 64;
  float sxr[8][4];
#pragma unroll
  for (int m = 0; m < 8; ++m)
#pragma unroll
    for (int v = 0; v < 4; ++v) sxr[m][v] = sx[r0 + m * 16 + v];
#pragma unroll
  for (int j = 0; j < 4; ++j) {
    const int col = c0 + j * 16 + l15;
    const float bv = bias[col];
    const float swc = sw[col];
#pragma unroll
    for (int m = 0; m < 8; ++m) {
      const int row = r0 + m * 16;
#pragma unroll
      for (int v = 0; v < 4; ++v)
        C[(size_t)(row + v) * N_TOT + col] =
            (float)acc[m][j][v] * (sxr[m][v] * swc) + bv;
    }
  }
}

extern "C" void kernel_launch(void* const* d_in, const int* in_sizes, int n_in,
                              void* d_out, int out_size, void* d_ws, size_t ws_size,
                              hipStream_t stream) {
  const float* x = (const float*)d_in[0];    // [2,2048,4096]
  const float* Wb = (const float*)d_in[1];   // [4096,4096]
  const float* bb = (const float*)d_in[2];   // [4096]
  const float* U = (const float*)d_in[3];    // [64,64,64]
  const float* V = (const float*)d_in[4];    // [64,64,64]
  const float* S = (const float*)d_in[5];    // [1]
  float* out = (float*)d_out;

  char* Wq = (char*)d_ws;                               // 16 MiB
  char* Xq = Wq + (size_t)4096 * 4096;                  // 16 MiB
  float* sw = (float*)(Xq + (size_t)4096 * 4096);       // 16 KiB
  float* sx = sw + 4096;                                // 16 KiB
  // Ut/Vt scratch in d_out's head (1 MiB each) — overwritten by the GEMM later
  float* Ut = (float*)d_out;
  float* Vt = Ut + 262144;

  trans_uv<<<2048, 256, 0, stream>>>(U, V, Ut, Vt);
  quant_rows<<<8192, 512, 0, stream>>>(Wb, Ut, Vt, S, x, Wq, Xq, sw, sx);

  gemm256<<<256, 512, 0, stream>>>(Xq, Wq, bb, sx, sw, out);
}